// Round 1
// baseline (1184.943 us; speedup 1.0000x reference)
//
#include <hip/hip_runtime.h>
#include <hip/hip_bf16.h>
#include <math.h>

#define B 2
#define T 2048
#define C 1024
#define NH 16
#define NKV 4
#define HD 64
#define M 64
#define GC 32
#define S_TOT (M + T)   // 2112
#define EPS 1e-6f

// ---------------------------------------------------------------- wave reduce
__device__ inline float wave_sum(float v) {
    #pragma unroll
    for (int off = 32; off; off >>= 1) v += __shfl_xor(v, off, 64);
    return v;
}

// ---------------------------------------------------------------- fp32 GEMM
// C[m,n] = sum_k A[m,k] * Bt[n,k]   (A: MxK row-major, Bt: NxK row-major)
// 128x128 tile, BK=16, 256 threads, 8x8 micro-tile. Dims must divide tiles.
#define GBM 128
#define GBN 128
#define GBK 16

__global__ __launch_bounds__(256) void gemm_abt(
    const float* __restrict__ A, const float* __restrict__ Bt,
    float* __restrict__ Cc, int Mm, int Nn, int Kk)
{
    __shared__ float As[GBK][GBM + 2];
    __shared__ float Bs[GBK][GBN + 2];
    const int bx = blockIdx.x;         // col tile
    const int by = blockIdx.y;         // row tile
    const int tid = threadIdx.x;
    const int tr = tid >> 4;           // 0..15
    const int tc = tid & 15;           // 0..15
    const int m0 = by * GBM, n0 = bx * GBN;

    float acc[8][8];
    #pragma unroll
    for (int i = 0; i < 8; ++i)
        #pragma unroll
        for (int j = 0; j < 8; ++j) acc[i][j] = 0.f;

    for (int k0 = 0; k0 < Kk; k0 += GBK) {
        #pragma unroll
        for (int p = 0; p < 8; ++p) {
            int flat = p * 256 + tid;
            int row = flat >> 4;       // 0..127
            int kk  = flat & 15;
            As[kk][row] = A[(size_t)(m0 + row) * Kk + k0 + kk];
            Bs[kk][row] = Bt[(size_t)(n0 + row) * Kk + k0 + kk];
        }
        __syncthreads();
        #pragma unroll
        for (int kk = 0; kk < GBK; ++kk) {
            float a[8], b[8];
            #pragma unroll
            for (int i = 0; i < 8; ++i) a[i] = As[kk][tr + 16 * i];
            #pragma unroll
            for (int j = 0; j < 8; ++j) b[j] = Bs[kk][tc + 16 * j];
            #pragma unroll
            for (int i = 0; i < 8; ++i)
                #pragma unroll
                for (int j = 0; j < 8; ++j) acc[i][j] += a[i] * b[j];
        }
        __syncthreads();
    }
    #pragma unroll
    for (int i = 0; i < 8; ++i)
        #pragma unroll
        for (int j = 0; j < 8; ++j)
            Cc[(size_t)(m0 + tr + 16 * i) * Nn + n0 + tc + 16 * j] = acc[i][j];
}

// ------------------------------------------------- gate + RoPE + RMS fusion
// one block per (b,t); wave w (of 4) handles q heads w,w+4,w+8,w+12 and kv head w
__global__ __launch_bounds__(256) void fuse_kernel(
    const float* __restrict__ x, const float* __restrict__ ve,
    const float* __restrict__ cosb, const float* __restrict__ sinb,
    const float* __restrict__ Wg,
    float* __restrict__ qbuf, const float* __restrict__ kbuf,
    const float* __restrict__ vbuf,
    float* __restrict__ kfull, float* __restrict__ vfull)
{
    const int bt = blockIdx.x;          // 0..B*T-1
    const int b  = bt >> 11;            // / T
    const int t  = bt & (T - 1);
    const int w  = threadIdx.x >> 6;    // wave 0..3
    const int l  = threadIdx.x & 63;
    const int i  = l & 31;
    const float c = cosb[t * 32 + i];
    const float s = sinb[t * 32 + i];

    // q heads: rope + rms, in place
    #pragma unroll
    for (int hq = 0; hq < 4; ++hq) {
        const int h = w + hq * 4;
        const size_t base = (size_t)bt * 1024 + h * 64;
        float x1 = qbuf[base + i];
        float x2 = qbuf[base + i + 32];
        float val = (l < 32) ? (x1 * c - x2 * s) : (x1 * s + x2 * c);
        float ss = wave_sum(val * val);
        float scale = rsqrtf(ss * (1.f / 64.f) + EPS) * 1.2f;
        qbuf[base + l] = val * scale;
    }
    // k head kv=w: rope + rms -> kfull
    {
        const size_t base = (size_t)bt * 256 + w * 64;
        float x1 = kbuf[base + i];
        float x2 = kbuf[base + i + 32];
        float val = (l < 32) ? (x1 * c - x2 * s) : (x1 * s + x2 * c);
        float ss = wave_sum(val * val);
        float scale = rsqrtf(ss * (1.f / 64.f) + EPS) * 1.2f;
        kfull[((size_t)(b * S_TOT) + M + t) * 256 + w * 64 + l] = val * scale;
    }
    // gate + ve add -> vfull
    {
        float g = 0.f;
        #pragma unroll
        for (int gi = 0; gi < GC; ++gi)
            g += x[(size_t)bt * 1024 + gi] * Wg[w * GC + gi];
        g = 3.f / (1.f + __expf(-g));
        const size_t base = (size_t)bt * 256 + w * 64;
        float vv = vbuf[base + l] + g * ve[base + l];
        vfull[((size_t)(b * S_TOT) + M + t) * 256 + w * 64 + l] = vv;
    }
}

// ------------------------------------------------------- memory token prep
__global__ __launch_bounds__(256) void mem_kernel(
    const float* __restrict__ mem_k, const float* __restrict__ mem_v,
    const float* __restrict__ vscal,
    float* __restrict__ kfull, float* __restrict__ vfull)
{
    const int bm = blockIdx.x;          // 0..B*M-1
    const int b = bm / M, m = bm % M;
    const int w = threadIdx.x >> 6, l = threadIdx.x & 63;
    const size_t src = ((size_t)m * NKV + w) * HD + l;
    float kvv = mem_k[src];
    float ss = wave_sum(kvv * kvv);
    float scale = rsqrtf(ss * (1.f / 64.f) + EPS) * 1.2f;
    const size_t dst = ((size_t)(b * S_TOT) + m) * 256 + w * 64 + l;
    kfull[dst] = kvv * scale;
    vfull[dst] = mem_v[src] * vscal[0];
}

// --------------------------------------------------------- flash attention
// block = (tt, h, b); 64 q-rows x full s sweep; 256 threads; fp32.
__global__ __launch_bounds__(256) void attn_kernel(
    const float* __restrict__ qf, const float* __restrict__ kf,
    const float* __restrict__ vf, float* __restrict__ y)
{
    __shared__ __align__(16) float Qs[64][68];
    __shared__ __align__(16) float KV[64][68];
    __shared__ __align__(16) float Ps[64][68];
    __shared__ float red[64][16];
    __shared__ float mrow[64], lrow[64], srow[64];

    const int tt = blockIdx.x, h = blockIdx.y, b = blockIdx.z;
    const int kv = h >> 2;              // GQA group
    const int t0 = tt * 64;
    const int tid = threadIdx.x;
    const int ty = tid >> 4;            // 0..15
    const int tx = tid & 15;            // 0..15

    float o[4][4];
    #pragma unroll
    for (int i = 0; i < 4; ++i)
        #pragma unroll
        for (int j = 0; j < 4; ++j) o[i][j] = 0.f;

    // load Q tile (64x64) via float4
    #pragma unroll
    for (int p = 0; p < 4; ++p) {
        int flat = p * 256 + tid;       // float4 index, 1024 total
        int rr = flat >> 4, dq = flat & 15;
        float4 v4 = *(const float4*)&qf[(((size_t)(b * T + t0 + rr)) * NH + h) * HD + dq * 4];
        *(float4*)&Qs[rr][dq * 4] = v4;
    }
    if (tid < 64) { mrow[tid] = -INFINITY; lrow[tid] = 0.f; }
    __syncthreads();

    const int nst = tt + 2;             // s-tiles: mem tile + tt causal + diagonal
    for (int st = 0; st < nst; ++st) {
        // K tile -> KV
        #pragma unroll
        for (int p = 0; p < 4; ++p) {
            int flat = p * 256 + tid;
            int rr = flat >> 4, dq = flat & 15;
            float4 v4 = *(const float4*)&kf[(((size_t)(b * S_TOT + st * 64 + rr)) * NKV + kv) * HD + dq * 4];
            *(float4*)&KV[rr][dq * 4] = v4;
        }
        __syncthreads();

        // scores: rows ty+16i, cols tx+16j
        float sc[4][4];
        #pragma unroll
        for (int i = 0; i < 4; ++i)
            #pragma unroll
            for (int j = 0; j < 4; ++j) sc[i][j] = 0.f;
        #pragma unroll
        for (int d4 = 0; d4 < 16; ++d4) {
            float4 a4[4], b4[4];
            #pragma unroll
            for (int i = 0; i < 4; ++i) a4[i] = *(const float4*)&Qs[ty + 16 * i][d4 * 4];
            #pragma unroll
            for (int j = 0; j < 4; ++j) b4[j] = *(const float4*)&KV[tx + 16 * j][d4 * 4];
            #pragma unroll
            for (int i = 0; i < 4; ++i)
                #pragma unroll
                for (int j = 0; j < 4; ++j)
                    sc[i][j] += a4[i].x * b4[j].x + a4[i].y * b4[j].y +
                                a4[i].z * b4[j].z + a4[i].w * b4[j].w;
        }
        const bool diag = (st == nst - 1);
        #pragma unroll
        for (int i = 0; i < 4; ++i) {
            float mloc = -INFINITY;
            #pragma unroll
            for (int j = 0; j < 4; ++j) {
                float v = sc[i][j] * 0.125f;
                if (diag && (tx + 16 * j) > (ty + 16 * i)) v = -INFINITY;
                sc[i][j] = v;
                mloc = fmaxf(mloc, v);
            }
            red[ty + 16 * i][tx] = mloc;
        }
        __syncthreads();
        if (tid < 64) {
            float mt = red[tid][0];
            #pragma unroll
            for (int xx = 1; xx < 16; ++xx) mt = fmaxf(mt, red[tid][xx]);
            float mo = mrow[tid];
            float mn = fmaxf(mo, mt);
            mrow[tid] = mn;
            srow[tid] = __expf(mo - mn);   // 0 on first tile (mo = -inf)
        }
        __syncthreads();
        #pragma unroll
        for (int i = 0; i < 4; ++i) {
            const int rr = ty + 16 * i;
            const float mn = mrow[rr];
            float ls = 0.f;
            #pragma unroll
            for (int j = 0; j < 4; ++j) {
                float pexp = __expf(sc[i][j] - mn);   // masked -> exp(-inf)=0
                Ps[rr][tx + 16 * j] = pexp;
                ls += pexp;
            }
            red[rr][tx] = ls;
            const float scl = srow[rr];
            #pragma unroll
            for (int j = 0; j < 4; ++j) o[i][j] *= scl;
        }
        __syncthreads();
        if (tid < 64) {
            float ls = 0.f;
            #pragma unroll
            for (int xx = 0; xx < 16; ++xx) ls += red[tid][xx];
            lrow[tid] = lrow[tid] * srow[tid] + ls;
        }
        // V tile -> KV (K no longer needed)
        #pragma unroll
        for (int p = 0; p < 4; ++p) {
            int flat = p * 256 + tid;
            int rr = flat >> 4, dq = flat & 15;
            float4 v4 = *(const float4*)&vf[(((size_t)(b * S_TOT + st * 64 + rr)) * NKV + kv) * HD + dq * 4];
            *(float4*)&KV[rr][dq * 4] = v4;
        }
        __syncthreads();

        // PV: rows ty+16i, cols tx*4+jj
        #pragma unroll 4
        for (int sr = 0; sr < 64; ++sr) {
            const float4 v4 = *(const float4*)&KV[sr][tx * 4];
            const float p0 = Ps[ty][sr];
            const float p1 = Ps[ty + 16][sr];
            const float p2 = Ps[ty + 32][sr];
            const float p3 = Ps[ty + 48][sr];
            o[0][0] += p0 * v4.x; o[0][1] += p0 * v4.y; o[0][2] += p0 * v4.z; o[0][3] += p0 * v4.w;
            o[1][0] += p1 * v4.x; o[1][1] += p1 * v4.y; o[1][2] += p1 * v4.z; o[1][3] += p1 * v4.w;
            o[2][0] += p2 * v4.x; o[2][1] += p2 * v4.y; o[2][2] += p2 * v4.z; o[2][3] += p2 * v4.w;
            o[3][0] += p3 * v4.x; o[3][1] += p3 * v4.y; o[3][2] += p3 * v4.z; o[3][3] += p3 * v4.w;
        }
        __syncthreads();
    }

    #pragma unroll
    for (int i = 0; i < 4; ++i) {
        const int rr = ty + 16 * i;
        const float inv = 1.f / lrow[rr];
        float4 v4 = make_float4(o[i][0] * inv, o[i][1] * inv, o[i][2] * inv, o[i][3] * inv);
        *(float4*)&y[(((size_t)(b * T + t0 + rr)) * NH + h) * HD + tx * 4] = v4;
    }
}

// ----------------------------------------------------------------- launcher
extern "C" void kernel_launch(void* const* d_in, const int* in_sizes, int n_in,
                              void* d_out, int out_size, void* d_ws, size_t ws_size,
                              hipStream_t stream)
{
    const float* x     = (const float*)d_in[0];
    const float* ve    = (const float*)d_in[1];
    const float* cosb  = (const float*)d_in[2];
    const float* sinb  = (const float*)d_in[3];
    const float* Wq    = (const float*)d_in[4];
    const float* Wk    = (const float*)d_in[5];
    const float* Wv    = (const float*)d_in[6];
    const float* Wproj = (const float*)d_in[7];
    const float* Wg    = (const float*)d_in[8];
    const float* memk  = (const float*)d_in[9];
    const float* memv  = (const float*)d_in[10];
    const float* vscal = (const float*)d_in[11];

    float* ws = (float*)d_ws;
    float* qbuf  = ws;                                  // 4096*1024
    float* kbuf  = qbuf + (size_t)4096 * 1024;          // 4096*256
    float* vbuf  = kbuf + (size_t)4096 * 256;           // 4096*256
    float* kfull = vbuf + (size_t)4096 * 256;           // B*S_TOT*256
    float* vfull = kfull + (size_t)B * S_TOT * 256;     // B*S_TOT*256
    float* ybuf  = vfull + (size_t)B * S_TOT * 256;     // 4096*1024
    float* out   = (float*)d_out;

    const dim3 blk(256);
    // projections: q (N=1024), k (N=256), v (N=256)
    gemm_abt<<<dim3(1024 / GBN, 4096 / GBM), blk, 0, stream>>>(x, Wq, qbuf, 4096, 1024, 1024);
    gemm_abt<<<dim3(256 / GBN, 4096 / GBM), blk, 0, stream>>>(x, Wk, kbuf, 4096, 256, 1024);
    gemm_abt<<<dim3(256 / GBN, 4096 / GBM), blk, 0, stream>>>(x, Wv, vbuf, 4096, 256, 1024);
    // gate + rope + rms fusion, memory tokens
    fuse_kernel<<<dim3(B * T), blk, 0, stream>>>(x, ve, cosb, sinb, Wg,
                                                 qbuf, kbuf, vbuf, kfull, vfull);
    mem_kernel<<<dim3(B * M), blk, 0, stream>>>(memk, memv, vscal, kfull, vfull);
    // attention
    attn_kernel<<<dim3(T / 64, NH, B), blk, 0, stream>>>(qbuf, kfull, vfull, ybuf);
    // output projection
    gemm_abt<<<dim3(1024 / GBN, 4096 / GBM), blk, 0, stream>>>(ybuf, Wproj, out, 4096, 1024, 1024);
}

// Round 2
// 207.509 us; speedup vs baseline: 5.7103x; 5.7103x over previous
//
#include <hip/hip_runtime.h>
#include <hip/hip_bf16.h>
#include <math.h>

#define B 2
#define T 2048
#define C 1024
#define NH 16
#define NKV 4
#define HD 64
#define M 64
#define GC 32
#define S_TOT (M + T)   // 2112
#define EPS 1e-6f

using bf16x8  = __attribute__((ext_vector_type(8))) __bf16;
using f32x4   = __attribute__((ext_vector_type(4))) float;
using ushort8 = __attribute__((ext_vector_type(8))) unsigned short;
using ushort4v= __attribute__((ext_vector_type(4))) unsigned short;

__device__ inline unsigned short f2bf(float f) {
    __bf16 h = (__bf16)f;
    return __builtin_bit_cast(unsigned short, h);
}
__device__ inline float wave_sum(float v) {
    #pragma unroll
    for (int off = 32; off; off >>= 1) v += __shfl_xor(v, off, 64);
    return v;
}

// ------------------------------------------------------------ fp32 -> bf16
__global__ __launch_bounds__(256) void cast_kernel(
    const float* __restrict__ src, unsigned short* __restrict__ dst, int n4)
{
    int i = blockIdx.x * 256 + threadIdx.x;
    if (i < n4) {
        float4 v = ((const float4*)src)[i];
        ushort4v o;
        o.x = f2bf(v.x); o.y = f2bf(v.y); o.z = f2bf(v.z); o.w = f2bf(v.w);
        ((ushort4v*)dst)[i] = o;
    }
}

// ------------------------------------------------------- bf16 MFMA GEMM
// C[m,n] = sum_k A[m,k]*Bt[n,k]; A: MxK bf16, Bt: NxK bf16, C: MxN fp32.
// 128x128 tile, BK=64, 256 threads (4 waves 2x2), 16x16x32 MFMA.
__global__ __launch_bounds__(256) void gemm_bf16(
    const unsigned short* __restrict__ A, const unsigned short* __restrict__ Bt,
    float* __restrict__ Cc, int Mm, int Nn, int Kk)
{
    __shared__ unsigned short As[128][72];
    __shared__ unsigned short Bs[128][72];
    const int tid = threadIdx.x;
    const int w = tid >> 6, lane = tid & 63, lx = lane & 15, hi = lane >> 4;
    const int wr = w >> 1, wc = w & 1;
    const int m0 = blockIdx.y * 128, n0 = blockIdx.x * 128;

    f32x4 acc[4][4];
    #pragma unroll
    for (int mi = 0; mi < 4; ++mi)
        #pragma unroll
        for (int ni = 0; ni < 4; ++ni) acc[mi][ni] = (f32x4){0.f, 0.f, 0.f, 0.f};

    for (int k0 = 0; k0 < Kk; k0 += 64) {
        #pragma unroll
        for (int p = 0; p < 4; ++p) {
            int flat = p * 256 + tid;
            int row = flat >> 3, kb = flat & 7;
            *(ushort8*)&As[row][kb * 8] =
                *(const ushort8*)&A[(size_t)(m0 + row) * Kk + k0 + kb * 8];
            *(ushort8*)&Bs[row][kb * 8] =
                *(const ushort8*)&Bt[(size_t)(n0 + row) * Kk + k0 + kb * 8];
        }
        __syncthreads();
        #pragma unroll
        for (int kk = 0; kk < 2; ++kk) {
            bf16x8 af[4], bfr[4];
            #pragma unroll
            for (int mi = 0; mi < 4; ++mi)
                af[mi] = *(const bf16x8*)&As[wr * 64 + mi * 16 + lx][kk * 32 + hi * 8];
            #pragma unroll
            for (int ni = 0; ni < 4; ++ni)
                bfr[ni] = *(const bf16x8*)&Bs[wc * 64 + ni * 16 + lx][kk * 32 + hi * 8];
            #pragma unroll
            for (int mi = 0; mi < 4; ++mi)
                #pragma unroll
                for (int ni = 0; ni < 4; ++ni)
                    acc[mi][ni] = __builtin_amdgcn_mfma_f32_16x16x32_bf16(
                        af[mi], bfr[ni], acc[mi][ni], 0, 0, 0);
        }
        __syncthreads();
    }
    #pragma unroll
    for (int mi = 0; mi < 4; ++mi)
        #pragma unroll
        for (int ni = 0; ni < 4; ++ni)
            #pragma unroll
            for (int r = 0; r < 4; ++r)
                Cc[(size_t)(m0 + wr * 64 + mi * 16 + hi * 4 + r) * Nn
                   + n0 + wc * 64 + ni * 16 + lx] = acc[mi][ni][r];
}

// ------------------------------------------------- gate + RoPE + RMS fusion
__global__ __launch_bounds__(256) void fuse_kernel(
    const float* __restrict__ x, const float* __restrict__ ve,
    const float* __restrict__ cosb, const float* __restrict__ sinb,
    const float* __restrict__ Wg, const float* __restrict__ qkv,
    unsigned short* __restrict__ qh, unsigned short* __restrict__ kfull,
    unsigned short* __restrict__ vfull)
{
    const int bt = blockIdx.x;
    const int b = bt >> 11, t = bt & (T - 1);
    const int w = threadIdx.x >> 6, l = threadIdx.x & 63, i = l & 31;
    const float c = cosb[t * 32 + i];
    const float s = sinb[t * 32 + i];
    const float* row = qkv + (size_t)bt * 1536;

    #pragma unroll
    for (int hq = 0; hq < 4; ++hq) {
        const int h = w + hq * 4;
        float x1 = row[h * 64 + i];
        float x2 = row[h * 64 + i + 32];
        float val = (l < 32) ? (x1 * c - x2 * s) : (x1 * s + x2 * c);
        float ss = wave_sum(val * val);
        float scale = rsqrtf(ss * (1.f / 64.f) + EPS) * 1.2f;
        qh[((size_t)(b * NH + h) * T + t) * 64 + l] = f2bf(val * scale);
    }
    {
        float x1 = row[1024 + w * 64 + i];
        float x2 = row[1024 + w * 64 + i + 32];
        float val = (l < 32) ? (x1 * c - x2 * s) : (x1 * s + x2 * c);
        float ss = wave_sum(val * val);
        float scale = rsqrtf(ss * (1.f / 64.f) + EPS) * 1.2f;
        kfull[((size_t)(b * NKV + w) * S_TOT + M + t) * 64 + l] = f2bf(val * scale);
    }
    {
        const float* xr = x + (size_t)bt * 1024;
        float g = 0.f;
        #pragma unroll
        for (int gi = 0; gi < GC; ++gi) g += xr[gi] * Wg[w * GC + gi];
        g = 3.f / (1.f + __expf(-g));
        float vv = row[1280 + w * 64 + l] + g * ve[(size_t)bt * 256 + w * 64 + l];
        vfull[((size_t)(b * NKV + w) * S_TOT + M + t) * 64 + l] = f2bf(vv);
    }
}

// ------------------------------------------------------- memory token prep
__global__ __launch_bounds__(256) void mem_kernel(
    const float* __restrict__ mem_k, const float* __restrict__ mem_v,
    const float* __restrict__ vscal,
    unsigned short* __restrict__ kfull, unsigned short* __restrict__ vfull)
{
    const int bm = blockIdx.x;
    const int b = bm >> 6, mr = bm & 63;
    const int w = threadIdx.x >> 6, l = threadIdx.x & 63;
    const size_t src = ((size_t)mr * NKV + w) * HD + l;
    float kvv = mem_k[src];
    float ss = wave_sum(kvv * kvv);
    float scale = rsqrtf(ss * (1.f / 64.f) + EPS) * 1.2f;
    const size_t dst = ((size_t)(b * NKV + w) * S_TOT + mr) * 64 + l;
    kfull[dst] = f2bf(kvv * scale);
    vfull[dst] = f2bf(mem_v[src] * vscal[0]);
}

// --------------------------------------------------------- MFMA flash attn
// block = (tt, h, b), 256 threads = 4 waves; wave w owns q rows 16w..16w+15.
__global__ __launch_bounds__(256) void attn_kernel(
    const unsigned short* __restrict__ qh, const unsigned short* __restrict__ kf,
    const unsigned short* __restrict__ vf, unsigned short* __restrict__ y)
{
    __shared__ unsigned short Ks[64][72];
    __shared__ unsigned short Vt[64][72];
    __shared__ unsigned short Ps[64][72];
    const int tt = blockIdx.x, h = blockIdx.y, b = blockIdx.z;
    const int kv = h >> 2, t0 = tt * 64;
    const int tid = threadIdx.x, w = tid >> 6, lane = tid & 63;
    const int lx = lane & 15, hi = lane >> 4;

    // hoisted Q fragments (A operand): m = lx -> q row t0+16w+lx, k = d
    bf16x8 aq[2];
    {
        const unsigned short* qp = qh + ((size_t)(b * NH + h) * T + t0 + 16 * w + lx) * 64;
        aq[0] = *(const bf16x8*)&qp[hi * 8];
        aq[1] = *(const bf16x8*)&qp[32 + hi * 8];
    }
    f32x4 o_acc[4];
    #pragma unroll
    for (int dt = 0; dt < 4; ++dt) o_acc[dt] = (f32x4){0.f, 0.f, 0.f, 0.f};
    float m_r[4], l_r[4];
    #pragma unroll
    for (int r = 0; r < 4; ++r) { m_r[r] = -INFINITY; l_r[r] = 0.f; }

    const unsigned short* kbase = kf + (size_t)(b * NKV + kv) * S_TOT * 64;
    const unsigned short* vbase = vf + (size_t)(b * NKV + kv) * S_TOT * 64;

    const int nst = tt + 2;
    for (int st = 0; st < nst; ++st) {
        const int s0 = st * 64;
        // stage K linear [s][d]
        #pragma unroll
        for (int p = 0; p < 2; ++p) {
            int flat = p * 256 + tid;
            int row = flat >> 3, kb = flat & 7;
            *(ushort8*)&Ks[row][kb * 8] =
                *(const ushort8*)&kbase[(size_t)(s0 + row) * 64 + kb * 8];
        }
        // stage V transposed [d][s]
        #pragma unroll
        for (int p = 0; p < 2; ++p) {
            int kb = p * 4 + w;
            ushort8 v8 = *(const ushort8*)&vbase[(size_t)(s0 + lane) * 64 + kb * 8];
            #pragma unroll
            for (int j = 0; j < 8; ++j) Vt[kb * 8 + j][lane] = (unsigned short)v8[j];
        }
        __syncthreads();

        // S = Q K^T for this wave's 16 rows
        f32x4 s_acc[4];
        #pragma unroll
        for (int nt = 0; nt < 4; ++nt) s_acc[nt] = (f32x4){0.f, 0.f, 0.f, 0.f};
        #pragma unroll
        for (int nt = 0; nt < 4; ++nt) {
            bf16x8 b0 = *(const bf16x8*)&Ks[nt * 16 + lx][hi * 8];
            bf16x8 b1 = *(const bf16x8*)&Ks[nt * 16 + lx][32 + hi * 8];
            s_acc[nt] = __builtin_amdgcn_mfma_f32_16x16x32_bf16(aq[0], b0, s_acc[nt], 0, 0, 0);
            s_acc[nt] = __builtin_amdgcn_mfma_f32_16x16x32_bf16(aq[1], b1, s_acc[nt], 0, 0, 0);
        }
        // scale + causal mask (diag tile only)
        const bool diag = (st == tt + 1);
        #pragma unroll
        for (int nt = 0; nt < 4; ++nt)
            #pragma unroll
            for (int r = 0; r < 4; ++r) {
                float v = s_acc[nt][r] * 0.125f;
                if (diag && (nt * 16 + lx) > (16 * w + hi * 4 + r)) v = -INFINITY;
                s_acc[nt][r] = v;
            }
        // row max (16-lane butterfly within hi-group)
        float mx[4];
        #pragma unroll
        for (int r = 0; r < 4; ++r)
            mx[r] = fmaxf(fmaxf(s_acc[0][r], s_acc[1][r]), fmaxf(s_acc[2][r], s_acc[3][r]));
        #pragma unroll
        for (int off = 1; off < 16; off <<= 1)
            #pragma unroll
            for (int r = 0; r < 4; ++r) mx[r] = fmaxf(mx[r], __shfl_xor(mx[r], off, 64));
        float resc[4];
        #pragma unroll
        for (int r = 0; r < 4; ++r) {
            float mn = fmaxf(m_r[r], mx[r]);
            resc[r] = __expf(m_r[r] - mn);
            m_r[r] = mn;
        }
        // P = exp(S - m) -> bf16 LDS; per-lane partial row sums
        #pragma unroll
        for (int r = 0; r < 4; ++r) {
            float ps = 0.f;
            #pragma unroll
            for (int nt = 0; nt < 4; ++nt) {
                float p = __expf(s_acc[nt][r] - m_r[r]);
                ps += p;
                Ps[16 * w + hi * 4 + r][nt * 16 + lx] = f2bf(p);
            }
            l_r[r] = l_r[r] * resc[r] + ps;
        }
        #pragma unroll
        for (int dt = 0; dt < 4; ++dt)
            #pragma unroll
            for (int r = 0; r < 4; ++r) o_acc[dt][r] *= resc[r];
        // O += P V  (A = P from LDS, B = V^T from LDS)
        #pragma unroll
        for (int kk = 0; kk < 2; ++kk) {
            bf16x8 pa = *(const bf16x8*)&Ps[16 * w + lx][kk * 32 + hi * 8];
            #pragma unroll
            for (int dt = 0; dt < 4; ++dt) {
                bf16x8 vb = *(const bf16x8*)&Vt[dt * 16 + lx][kk * 32 + hi * 8];
                o_acc[dt] = __builtin_amdgcn_mfma_f32_16x16x32_bf16(pa, vb, o_acc[dt], 0, 0, 0);
            }
        }
        __syncthreads();
    }

    // final l reduce + write y bf16 [b][t][h*64+d]
    float lt[4];
    #pragma unroll
    for (int r = 0; r < 4; ++r) {
        float v = l_r[r];
        #pragma unroll
        for (int off = 1; off < 16; off <<= 1) v += __shfl_xor(v, off, 64);
        lt[r] = 1.f / v;
    }
    #pragma unroll
    for (int dt = 0; dt < 4; ++dt)
        #pragma unroll
        for (int r = 0; r < 4; ++r) {
            int t = t0 + 16 * w + hi * 4 + r;
            y[((size_t)(b * T) + t) * 1024 + h * 64 + dt * 16 + lx] =
                f2bf(o_acc[dt][r] * lt[r]);
        }
}

// ----------------------------------------------------------------- launcher
extern "C" void kernel_launch(void* const* d_in, const int* in_sizes, int n_in,
                              void* d_out, int out_size, void* d_ws, size_t ws_size,
                              hipStream_t stream)
{
    const float* x     = (const float*)d_in[0];
    const float* ve    = (const float*)d_in[1];
    const float* cosb  = (const float*)d_in[2];
    const float* sinb  = (const float*)d_in[3];
    const float* Wq    = (const float*)d_in[4];
    const float* Wk    = (const float*)d_in[5];
    const float* Wv    = (const float*)d_in[6];
    const float* Wproj = (const float*)d_in[7];
    const float* Wg    = (const float*)d_in[8];
    const float* memk  = (const float*)d_in[9];
    const float* memv  = (const float*)d_in[10];
    const float* vscal = (const float*)d_in[11];

    unsigned short* xh    = (unsigned short*)d_ws;
    unsigned short* wqkv  = xh + (size_t)4096 * 1024;
    unsigned short* wproj = wqkv + (size_t)1536 * 1024;
    unsigned short* qhb   = wproj + (size_t)1024 * 1024;
    unsigned short* kfull = qhb + (size_t)4096 * 1024;
    unsigned short* vfull = kfull + (size_t)B * NKV * S_TOT * 64;
    float* qkvf = (float*)(vfull + (size_t)B * NKV * S_TOT * 64);
    unsigned short* ybuf = xh;   // alias: xh dead after QKV GEMM
    float* out = (float*)d_out;

    const dim3 blk(256);
    cast_kernel<<<dim3(4096), blk, 0, stream>>>(x, xh, 1048576);
    cast_kernel<<<dim3(1024), blk, 0, stream>>>(Wq, wqkv, 262144);
    cast_kernel<<<dim3(256),  blk, 0, stream>>>(Wk, wqkv + (size_t)1024 * 1024, 65536);
    cast_kernel<<<dim3(256),  blk, 0, stream>>>(Wv, wqkv + (size_t)1280 * 1024, 65536);
    cast_kernel<<<dim3(1024), blk, 0, stream>>>(Wproj, wproj, 262144);

    gemm_bf16<<<dim3(12, 32), blk, 0, stream>>>(xh, wqkv, qkvf, 4096, 1536, 1024);
    fuse_kernel<<<dim3(B * T), blk, 0, stream>>>(x, ve, cosb, sinb, Wg, qkvf,
                                                 qhb, kfull, vfull);
    mem_kernel<<<dim3(B * M), blk, 0, stream>>>(memk, memv, vscal, kfull, vfull);
    attn_kernel<<<dim3(T / 64, NH, B), blk, 0, stream>>>(qhb, kfull, vfull, ybuf);
    gemm_bf16<<<dim3(8, 32), blk, 0, stream>>>(ybuf, wproj, out, 4096, 1024, 1024);
}